// Round 14
// baseline (5049.342 us; speedup 1.0000x reference)
//
#include <hip/hip_runtime.h>

// RNN_85117661872189 on gfx950 — round 14: coalesced weight streaming.
// r8/r9/r13 identical counters proved: compiler reloads 46 quads/thread/step
// from L2 regardless of source tricks; reloads were 1KB-strided per lane
// (64 lines/wave-load). Fix: group-major wstr[g][tid] layout -> each wave-load
// is 1KB contiguous (16 lines), issued right after the barrier (h-independent).
// LDS 19 groups (157.7KB max), stream 45 groups. Math = verified GSTEP builtin.
// d_in[0] input_seq [2048][128] i32; f32: emb[128][128], Wxh_w[512][128],
// Wxh_b[512], Whh_w[512][512], Whh_b[512], dec_w[128][512], dec_b[128].
// Output f32 [2048][128][128].

#define TT 2048
#define BB 128
#define HH 512
#define OO 128
#define MAGIC 123456.0f
#define NLDSG 19   // u32x4 weight groups in LDS (groups 45..63)
#define NSTRG 45   // u32x4 weight groups streamed from L2 (groups 0..44)

typedef _Float16 h2_t __attribute__((ext_vector_type(2)));
typedef unsigned int u32x4 __attribute__((ext_vector_type(4)));
union UF { unsigned int u; float f; h2_t h; unsigned short us[2]; };

__device__ __forceinline__ unsigned int packf16(float a, float b) {
  UF r; r.h[0] = (_Float16)a; r.h[1] = (_Float16)b; return r.u;
}
__device__ __forceinline__ float dot2a(unsigned int a, unsigned int b, float c) {
  UF x, y; x.u = a; y.u = b;
#if __has_builtin(__builtin_amdgcn_fdot2)
  return __builtin_amdgcn_fdot2(x.h, y.h, c, false);   // v_dot2_f32_f16
#else
  return fmaf((float)x.h[1], (float)y.h[1], fmaf((float)x.h[0], (float)y.h[0], c));
#endif
}
__device__ __forceinline__ unsigned short f16bits(float x) {
  UF r; r.h[0] = (_Float16)x; r.h[1] = (_Float16)0.f; return r.us[0];
}
__device__ __forceinline__ float f16tof(unsigned short u) {
  UF r; r.us[0] = u; r.us[1] = 0; return (float)r.h[0];
}
__device__ __forceinline__ float tanh_fast(float x) {  // x pre-clamped
  float e = __expf(2.0f * x);
  return 1.0f - 2.0f / (e + 1.0f);
}
__device__ __forceinline__ float sanz(float x) {
  return (x >= -1e20f && x <= 1e20f) ? x : 0.f;
}
__device__ __forceinline__ unsigned int rdlane(unsigned int v, int l) {
#if __has_builtin(__builtin_amdgcn_readlane)
  return (unsigned int)__builtin_amdgcn_readlane((int)v, l);
#else
  return (unsigned int)__shfl((int)v, l, 64);
#endif
}

// ---- k_init / k_pre / k_pack / k_packd (unchanged, proven) ----
extern "C" __global__ void k_init(float* __restrict__ mk) {
  if (threadIdx.x < 8) mk[threadIdx.x] = 0.f;
}

extern "C" __global__ __launch_bounds__(512)
void k_pre(const float* __restrict__ emb, const float* __restrict__ wxh,
           const float* __restrict__ bxh, const float* __restrict__ bhh,
           float* __restrict__ P, float* __restrict__ mk) {
  const int id = blockIdx.x;
  const int j = threadIdx.x;
  const float4* er = (const float4*)(emb + id * 128);
  const float4* wr = (const float4*)(wxh + j * 128);
  float acc = 0.f;
  #pragma unroll
  for (int c = 0; c < 32; ++c) {
    const float4 e = er[c], w = wr[c];
    acc = fmaf(e.x, w.x, fmaf(e.y, w.y, fmaf(e.z, w.z, fmaf(e.w, w.w, acc))));
  }
  P[id * HH + j] = acc + bxh[j] + bhh[j];
  if (id == 0 && j == 0) mk[0] = MAGIC;
}

extern "C" __global__ __launch_bounds__(256)
void k_pack(const float* __restrict__ whh, unsigned int* __restrict__ wpack) {
  const int row = blockIdx.x;
  const int pd = threadIdx.x;
  const float2 w = *(const float2*)(whh + row * 512 + 2 * pd);
  wpack[row * 256 + pd] = packf16(w.x, w.y);
}

// ---- k_packS: group-major stream layout wstr[g][row] (coalesced reads) ----
extern "C" __global__ __launch_bounds__(512)
void k_packS(const unsigned int* __restrict__ wpack, u32x4* __restrict__ wstr4) {
  const int g = blockIdx.x;        // 0..63
  const int t = threadIdx.x;       // row
  const u32x4* src = (const u32x4*)wpack + (size_t)t * 64 + g;
  wstr4[(size_t)g * 512 + t] = *src;
}

extern "C" __global__ __launch_bounds__(256)
void k_packd(const float* __restrict__ dw, uint4* __restrict__ decP4) {
  const int id = blockIdx.x * 256 + threadIdx.x;
  const int c4 = id >> 7, o = id & 127;
  const float* src = dw + o * 512 + 8 * c4;
  uint4 v;
  v.x = packf16(src[0], src[1]);
  v.y = packf16(src[2], src[3]);
  v.z = packf16(src[4], src[5]);
  v.w = packf16(src[6], src[7]);
  decP4[id] = v;
}

// group g covers pair-dwords 4g..4g+3; lane g holds them in hv (verified r7).
#define GSTEP(W4, g)                                    \
  {                                                     \
    a0 = dot2a((W4).x, rdlane(hv.x, (g)), a0);          \
    a1 = dot2a((W4).y, rdlane(hv.y, (g)), a1);          \
    a2 = dot2a((W4).z, rdlane(hv.z, (g)), a2);          \
    a3 = dot2a((W4).w, rdlane(hv.w, (g)), a3);          \
  }

// ---- k_rec: 2048 steps; one WG (512 thr) per batch row; thread = one h-row ----
extern "C" __global__
__attribute__((amdgpu_flat_work_group_size(512, 512), amdgpu_waves_per_eu(2, 2)))
void k_rec(const int* __restrict__ idx, const float* __restrict__ P,
           const u32x4* __restrict__ wstr4,
           float* __restrict__ hstate, unsigned short* __restrict__ ring16,
           float* __restrict__ mk, int t0, int nT) {
  extern __shared__ __align__(16) unsigned char smem[];
  u32x4* wl4 = (u32x4*)smem;                                    // [NLDSG][512] 155,648 B
  unsigned short* hb16 = (unsigned short*)(smem + NLDSG * 512 * 16);  // [2][512]
  const uint4* hb4 = (const uint4*)hb16;
  const int tid = threadIdx.x;
  const int b = blockIdx.x;
  const int lane = tid & 63;
  if (t0 == 0 && b == 0 && tid == 0) mk[1] = MAGIC;

  #pragma unroll
  for (int s = 0; s < NLDSG; ++s)                               // groups 45..63 -> LDS
    wl4[s * 512 + tid] = wstr4[(size_t)(NSTRG + s) * 512 + tid];  // coalesced

  const float h0 = (t0 == 0) ? 0.f : hstate[b * HH + tid];
  hb16[tid] = f16bits(h0);
  float hlast = h0;
  __syncthreads();

  for (int tl = 0; tl < nT; ++tl) {
    const int rb = tl & 1, wb = rb ^ 1;
    const int id = idx[(t0 + tl) * BB + b];    // wave-uniform
    const float pj = P[id * HH + tid];
    const uint4 hv = hb4[rb * 64 + lane];      // lane's 4 h pair-dwords
    float a0 = 0.f, a1 = 0.f, a2 = 0.f, a3 = 0.f;
    #pragma unroll
    for (int s = 0; s < NLDSG; ++s) {          // LDS groups (data ready at once)
      const u32x4 w4 = wl4[s * 512 + tid];     // conflict-free b128
      GSTEP(w4, NSTRG + s);
    }
    #pragma unroll
    for (int g = 0; g < NSTRG; ++g) {          // L2 stream: 1KB contiguous per wave-load
      const u32x4 w4 = wstr4[(size_t)g * 512 + tid];
      GSTEP(w4, g);
    }
    float s = a0 + a1 + a2 + a3 + pj;
    s = fminf(fmaxf(s, -30.f), 30.f);          // IEEE min/max drop NaN
    const float hvf = tanh_fast(s);
    const unsigned short h16 = f16bits(hvf);
    hb16[wb * 512 + tid] = h16;
    ring16[((size_t)tl * BB + b) * HH + tid] = h16;
    hlast = hvf;
    __syncthreads();                           // h[wb] visible for next step
  }
  hstate[b * HH + tid] = hlast;
  if (t0 == 0 && b == 0 && tid == 0) mk[2] = MAGIC;
}

// ---- k_chk: recompute steps 0/1 for b=0 in plain HIP; flag mismatches ----
extern "C" __global__ __launch_bounds__(512)
void k_chk(const int* __restrict__ idx, const float* __restrict__ P,
           const unsigned int* __restrict__ wpack,
           const unsigned short* __restrict__ ring16, float* __restrict__ mk) {
  __shared__ unsigned short h1s[512];
  const int j = threadIdx.x;
  h1s[j] = ring16[j];
  __syncthreads();
  {
    const float pj = P[idx[0] * HH + j];
    const float s = fminf(fmaxf(pj, -30.f), 30.f);
    const float d = fabsf(f16tof(h1s[j]) - f16tof(f16bits(tanh_fast(s))));
    if (d > 0.02f) mk[5] = 7.f;
  }
  {
    const unsigned int* wr = wpack + (size_t)j * 256;
    const unsigned int* hp = (const unsigned int*)h1s;
    float a0 = 0.f, a1 = 0.f, a2 = 0.f, a3 = 0.f;
    for (int g = 0; g < 64; ++g) {
      a0 = dot2a(wr[4 * g + 0], hp[4 * g + 0], a0);
      a1 = dot2a(wr[4 * g + 1], hp[4 * g + 1], a1);
      a2 = dot2a(wr[4 * g + 2], hp[4 * g + 2], a2);
      a3 = dot2a(wr[4 * g + 3], hp[4 * g + 3], a3);
    }
    const float pj = P[idx[BB] * HH + j];
    const float s = fminf(fmaxf((a0 + a1) + (a2 + a3) + pj, -30.f), 30.f);
    const float d = fabsf(f16tof(ring16[BB * HH + j]) - f16tof(f16bits(tanh_fast(s))));
    if (d > 0.02f) mk[4] = 7.f;
  }
}

// ---- k_dec: out rows = ring(f16) · decP + dec_b (unchanged) ----
extern "C" __global__ __launch_bounds__(512)
void k_dec(const uint4* __restrict__ ring4, const uint4* __restrict__ decP4,
           const float* __restrict__ decb, float* __restrict__ out,
           float* __restrict__ mk, int t0) {
  extern __shared__ __align__(16) unsigned char smem[];
  uint4* hl4 = (uint4*)smem;
  const int tid = threadIdx.x;
  const size_t r0 = (size_t)blockIdx.x * 64;
  #pragma unroll
  for (int i = 0; i < 8; ++i) {
    const int u = i * 512 + tid;
    hl4[u] = ring4[(r0 + (u >> 6)) * 64 + (u & 63)];
  }
  __syncthreads();
  const int oq = tid & 31, tq = tid >> 5;
  float acc[4][4];
  #pragma unroll
  for (int r = 0; r < 4; ++r)
    #pragma unroll
    for (int s = 0; s < 4; ++s) acc[r][s] = 0.f;
  #pragma unroll 2
  for (int c4 = 0; c4 < 64; ++c4) {
    uint4 h4[4], d4[4];
    #pragma unroll
    for (int s = 0; s < 4; ++s) h4[s] = hl4[(tq + 16 * s) * 64 + c4];
    #pragma unroll
    for (int r = 0; r < 4; ++r) d4[r] = decP4[c4 * 128 + oq + 32 * r];
    #pragma unroll
    for (int r = 0; r < 4; ++r)
      #pragma unroll
      for (int s = 0; s < 4; ++s) {
        acc[r][s] = dot2a(d4[r].x, h4[s].x, acc[r][s]);
        acc[r][s] = dot2a(d4[r].y, h4[s].y, acc[r][s]);
        acc[r][s] = dot2a(d4[r].z, h4[s].z, acc[r][s]);
        acc[r][s] = dot2a(d4[r].w, h4[s].w, acc[r][s]);
      }
  }
  #pragma unroll
  for (int r = 0; r < 4; ++r) {
    const float db = decb[oq + 32 * r];
    #pragma unroll
    for (int s = 0; s < 4; ++s) {
      const size_t g = r0 + tq + 16 * s;
      out[((size_t)t0 * BB + g) * OO + oq + 32 * r] = sanz(acc[r][s] + db);
    }
  }
  if (t0 == 0 && blockIdx.x == 0 && tid == 0) mk[3] = MAGIC;
}

// ---- k_probe ----
extern "C" __global__ void k_probe(const float* __restrict__ mk, float* __restrict__ out,
                                   int wsTooSmall) {
  if (wsTooSmall)     { out[0] = 100000.f; return; }
  if (mk[0] != MAGIC) { out[0] = 200000.f; return; }
  if (mk[1] != MAGIC) { out[0] = 300000.f; return; }
  if (mk[2] != MAGIC) { out[0] = 400000.f; return; }
  if (mk[3] != MAGIC) { out[0] = 500000.f; return; }
  if (mk[5] == 7.f)   { out[0] = 600000.f; return; }
  if (mk[4] == 7.f)   { out[0] = 700000.f; return; }
}

extern "C" void kernel_launch(void* const* d_in, const int* in_sizes, int n_in,
                              void* d_out, int out_size, void* d_ws, size_t ws_size,
                              hipStream_t stream) {
  (void)in_sizes; (void)n_in; (void)out_size;
  const int* idx = (const int*)d_in[0];
  const float* emb = (const float*)d_in[1];
  const float* wxh = (const float*)d_in[2];
  const float* bxh = (const float*)d_in[3];
  const float* whh = (const float*)d_in[4];
  const float* bhh = (const float*)d_in[5];
  const float* dw  = (const float*)d_in[6];
  const float* db  = (const float*)d_in[7];
  float* out = (float*)d_out;

  char* ws = (char*)d_ws;
  float* P = (float*)ws;                                    // @0        256 KB
  float* hstate = (float*)(ws + (256 << 10));               // @256 KB   256 KB
  float* mk = (float*)(ws + (512 << 10));                   // @512 KB     4 KB
  unsigned int* wpack = (unsigned int*)(ws + (516 << 10));  // @516 KB   512 KB
  u32x4* wstr4 = (u32x4*)(ws + (1028 << 10));               // @1028 KB  512 KB
  uint4* decP4 = (uint4*)(ws + (1540 << 10));               // @1540 KB  128 KB
  unsigned short* ring16 = (unsigned short*)(ws + (1668 << 10));  // @1668 KB

  int chunkT = 0;
  const int opts[8] = {2048, 1024, 768, 512, 256, 128, 32, 8};
  for (int i = 0; i < 8; ++i) {
    const size_t need = (size_t)(1668 << 10) + (size_t)opts[i] * BB * HH * 2;
    if (ws_size >= need) { chunkT = opts[i]; break; }
  }
  if (chunkT == 0) {
    k_probe<<<1, 1, 0, stream>>>(nullptr, out, 1);
    return;
  }

  const int ldsRec = NLDSG * 512 * 16 + 2048;  // 157,696 B (<= 160 KiB cap)
  const int ldsDec = 64 * 64 * 16;             //  65,536 B
  (void)hipFuncSetAttribute(reinterpret_cast<const void*>(k_rec),
                            hipFuncAttributeMaxDynamicSharedMemorySize, ldsRec);
  (void)hipFuncSetAttribute(reinterpret_cast<const void*>(k_dec),
                            hipFuncAttributeMaxDynamicSharedMemorySize, ldsDec);

  k_init<<<1, 64, 0, stream>>>(mk);
  k_pre<<<128, 512, 0, stream>>>(emb, wxh, bxh, bhh, P, mk);
  k_pack<<<512, 256, 0, stream>>>(whh, wpack);
  k_packS<<<64, 512, 0, stream>>>(wpack, wstr4);
  k_packd<<<32, 256, 0, stream>>>(dw, decP4);
  bool first = true;
  for (int t0 = 0; t0 < TT; t0 += chunkT) {
    k_rec<<<BB, 512, ldsRec, stream>>>(idx, P, wstr4, hstate, ring16, mk, t0, chunkT);
    if (first) {
      k_chk<<<1, 512, 0, stream>>>(idx, P, wpack, ring16, mk);
      first = false;
    }
    k_dec<<<chunkT * 2, 512, ldsDec, stream>>>((const uint4*)ring16, decP4, db, out, mk, t0);
  }
  k_probe<<<1, 1, 0, stream>>>(mk, out, 0);
}